// Round 1
// baseline (73.045 us; speedup 1.0000x reference)
//
#include <hip/hip_runtime.h>

// Ordered product of 4,194,304 (+1 repeat) 2x2 matrices, v = e0^T * M.
// float4 encodes a row-major 2x2: (x y ; z w).

__device__ __forceinline__ float4 mm(const float4 A, const float4 B) {
    // C = A @ B
    float4 C;
    C.x = fmaf(A.x, B.x, A.y * B.z);
    C.y = fmaf(A.x, B.y, A.y * B.w);
    C.z = fmaf(A.z, B.x, A.w * B.z);
    C.w = fmaf(A.z, B.y, A.w * B.w);
    return C;
}

// Phase 1: 4096 blocks x 256 threads, 4 tokens/thread (one coalesced int4).
// Each block writes the ordered product of its 1024-token tile.
__global__ __launch_bounds__(256) void scan_phase1(const int4* __restrict__ tok4,
                                                   const float4* __restrict__ ls,
                                                   float4* __restrict__ partials) {
    const int tid = threadIdx.x;
    const int gid = blockIdx.x * 256 + tid;

    const int4 t = tok4[gid];                 // coalesced 16B token load
    float4 m = ls[t.x];                       // 2KB table -> L1 hits
    m = mm(m, ls[t.y]);
    m = mm(m, ls[t.z]);
    m = mm(m, ls[t.w]);

    __shared__ float4 sm[256];
    sm[tid] = m;
    __syncthreads();
    #pragma unroll
    for (int s = 128; s > 0; s >>= 1) {       // ordered tree: left @ right
        if (tid < s) sm[tid] = mm(sm[tid], sm[tid + s]);
        __syncthreads();
    }
    if (tid == 0) partials[blockIdx.x] = sm[0];
}

// Phase 2: single block reduces 4096 partials in order, applies the doubled
// last-token matrix, writes row 0 (since v0 = [1,0]).
__global__ __launch_bounds__(256) void scan_phase2(const float4* __restrict__ partials,
                                                   const int* __restrict__ tokens,
                                                   const float4* __restrict__ ls,
                                                   float* __restrict__ out) {
    const int tid = threadIdx.x;
    float4 m = make_float4(1.f, 0.f, 0.f, 1.f);
    #pragma unroll
    for (int k = 0; k < 16; ++k)              // 16 consecutive partials/thread
        m = mm(m, partials[tid * 16 + k]);

    __shared__ float4 sm[256];
    sm[tid] = m;
    __syncthreads();
    #pragma unroll
    for (int s = 128; s > 0; s >>= 1) {
        if (tid < s) sm[tid] = mm(sm[tid], sm[tid + s]);
        __syncthreads();
    }
    if (tid == 0) {
        const float4 M = mm(sm[0], ls[tokens[4194304 - 1]]);  // last applied twice
        out[0] = M.x;
        out[1] = M.y;
    }
}

extern "C" void kernel_launch(void* const* d_in, const int* in_sizes, int n_in,
                              void* d_out, int out_size, void* d_ws, size_t ws_size,
                              hipStream_t stream) {
    const int*    tokens = (const int*)d_in[0];     // (T,) int32
    const float4* ls     = (const float4*)d_in[1];  // (128,2,2) f32 == 128 x float4
    // d_in[2] ("final") is unused by the reference.
    float*  out      = (float*)d_out;               // 2 floats
    float4* partials = (float4*)d_ws;               // 4096 * 16B = 64 KB scratch

    scan_phase1<<<4096, 256, 0, stream>>>((const int4*)tokens, ls, partials);
    scan_phase2<<<1, 256, 0, stream>>>(partials, tokens, ls, out);
}

// Round 2
// 71.824 us; speedup vs baseline: 1.0170x; 1.0170x over previous
//
#include <hip/hip_runtime.h>

// Ordered product of 4,194,304 (+1 repeat) 2x2 float32 matrices; out = e0^T * M.
// float4 encodes a row-major 2x2: (x y ; z w).

#define T_TOKENS 4194304
#define TPB      256
#define TOK_PER_THREAD 8
#define BLOCKS   (T_TOKENS / (TPB * TOK_PER_THREAD))   // 2048

__device__ __forceinline__ float4 mm(const float4 A, const float4 B) {
    float4 C;
    C.x = fmaf(A.x, B.x, A.y * B.z);
    C.y = fmaf(A.x, B.y, A.y * B.w);
    C.z = fmaf(A.z, B.x, A.w * B.z);
    C.w = fmaf(A.z, B.y, A.w * B.w);
    return C;
}

// Barrier-free ordered product across the 64-lane wave via xor-butterfly.
// At each step, the lane holding the EARLIER segment supplies the LEFT operand,
// so non-commutative order is preserved. All lanes end with the wave product.
__device__ __forceinline__ float4 wave_reduce_mm(float4 m, int lane) {
    #pragma unroll
    for (int s = 1; s < 64; s <<= 1) {
        float4 o;
        o.x = __shfl_xor(m.x, s, 64);
        o.y = __shfl_xor(m.y, s, 64);
        o.z = __shfl_xor(m.z, s, 64);
        o.w = __shfl_xor(m.w, s, 64);
        m = ((lane & s) == 0) ? mm(m, o) : mm(o, m);
    }
    return m;
}

// Phase 1: 2048 blocks x 256 threads, 8 tokens/thread (two int4 loads).
// Exactly 32 waves/CU -> single occupancy round. One barrier per block.
__global__ __launch_bounds__(256) void scan_phase1(const int4* __restrict__ tok4,
                                                   const float4* __restrict__ ls,
                                                   float4* __restrict__ partials) {
    const int tid = threadIdx.x;
    const int g   = blockIdx.x * TPB + tid;

    const int4 a = tok4[2 * g];
    const int4 b = tok4[2 * g + 1];

    float4 m = ls[a.x];                 // 2 KB table: L1-resident gathers
    m = mm(m, ls[a.y]);
    m = mm(m, ls[a.z]);
    m = mm(m, ls[a.w]);
    m = mm(m, ls[b.x]);
    m = mm(m, ls[b.y]);
    m = mm(m, ls[b.z]);
    m = mm(m, ls[b.w]);

    m = wave_reduce_mm(m, tid & 63);

    __shared__ float4 sm[4];
    if ((tid & 63) == 0) sm[tid >> 6] = m;
    __syncthreads();
    if (tid == 0)
        partials[blockIdx.x] = mm(mm(sm[0], sm[1]), mm(sm[2], sm[3]));
}

// Phase 2: one block reduces 2048 partials in order, applies the doubled
// last-token matrix, writes row 0 (v0 = [1,0]).
__global__ __launch_bounds__(256) void scan_phase2(const float4* __restrict__ partials,
                                                   const int* __restrict__ tokens,
                                                   const float4* __restrict__ ls,
                                                   float* __restrict__ out) {
    const int tid = threadIdx.x;
    float4 m = partials[tid * 8];
    #pragma unroll
    for (int k = 1; k < 8; ++k)
        m = mm(m, partials[tid * 8 + k]);

    m = wave_reduce_mm(m, tid & 63);

    __shared__ float4 sm[4];
    if ((tid & 63) == 0) sm[tid >> 6] = m;
    __syncthreads();
    if (tid == 0) {
        float4 M = mm(mm(sm[0], sm[1]), mm(sm[2], sm[3]));
        M = mm(M, ls[tokens[T_TOKENS - 1]]);   // last token applied twice
        out[0] = M.x;
        out[1] = M.y;
    }
}

extern "C" void kernel_launch(void* const* d_in, const int* in_sizes, int n_in,
                              void* d_out, int out_size, void* d_ws, size_t ws_size,
                              hipStream_t stream) {
    const int*    tokens = (const int*)d_in[0];     // (T,) int32
    const float4* ls     = (const float4*)d_in[1];  // (128,2,2) f32 == 128 x float4
    float*  out      = (float*)d_out;               // 2 floats
    float4* partials = (float4*)d_ws;               // 2048 * 16 B = 32 KB scratch

    scan_phase1<<<BLOCKS, TPB, 0, stream>>>((const int4*)tokens, ls, partials);
    scan_phase2<<<1, TPB, 0, stream>>>(partials, tokens, ls, out);
}